// Round 1
// baseline (14885.051 us; speedup 1.0000x reference)
//
#include <hip/hip_runtime.h>
#include <hip/hip_bf16.h>

using bf16 = __hip_bfloat16;

#define DEVINL __device__ __forceinline__

DEVINL float b2f(bf16 v) { return __bfloat162float(v); }
DEVINL bf16 f2b(float v) { return __float2bfloat16(v); }

// problem dims
static constexpr int HW_ = 64 * 64;

// workspace arena (bytes). Lifetime-aliased; peak ~215.5 MB.
static constexpr size_t OFF_F2S   = 0;           // bf16 162*32*4096  (dead after conv1)
static constexpr size_t OFF_E1    = 42467328;    // bf16 162*48*4096  (dead after e2)
static constexpr size_t OFF_E2    = 106168320;   // bf16 162*64*4096  (dead after e3)
static constexpr size_t OFF_E3    = 42467328;    // bf16 162*32*4096  (reuse E1; alive to end)
static constexpr size_t OFF_X1    = 84934656;    // bf16 162*96*4096  (reuse E2+; dead after conv2)
static constexpr size_t OFF_X2    = 0;           // bf16 162*128*1024 (reuse F2S)
static constexpr size_t OFF_X3    = 84934656;    // bf16 162*128*1024 (reuse X1)
static constexpr size_t OFF_X4    = 127401984;   // bf16 162*64*1024
static constexpr size_t OFF_XD    = 148635648;   // bf16 162*32*4096
static constexpr size_t OFF_SCORE = 0;           // f32  2*81*4096    (reuse X2, dead)
static constexpr size_t OFF_STATS = 212336640;   // f32  5*512
static constexpr size_t OFF_P1    = 212346880;   // f32  2*96*4096

// ---------------------------------------------------------------- sampler
__global__ __launch_bounds__(256) void sample_kernel(
    const float* __restrict__ f2, const float* __restrict__ coords, bf16* __restrict__ f2s)
{
  const int n = blockIdx.z, b = n / 81, ij = n % 81;
  const float di = (float)(ij / 9) - 4.f, dj = (float)(ij % 9) - 4.f;
  const int w = threadIdx.x & 63;
  const int h = blockIdx.x * 4 + (threadIdx.x >> 6);
  const float x = coords[((size_t)(b * 2 + 0)) * HW_ + h * 64 + w] + di;
  const float y = coords[((size_t)(b * 2 + 1)) * HW_ + h * 64 + w] + dj;
  const float x0f = floorf(x), y0f = floorf(y);
  const int x0 = (int)x0f, y0 = (int)y0f;
  const float wx1 = x - x0f, wx0 = 1.f - wx1;
  const float wy1 = y - y0f, wy0 = 1.f - wy1;
  const bool vx0 = (unsigned)x0 < 64u, vx1 = (unsigned)(x0 + 1) < 64u;
  const bool vy0 = (unsigned)y0 < 64u, vy1 = (unsigned)(y0 + 1) < 64u;
  const int x0c = min(max(x0, 0), 63), x1c = min(max(x0 + 1, 0), 63);
  const int y0c = min(max(y0, 0), 63), y1c = min(max(y0 + 1, 0), 63);
  const float w00 = (vy0 && vx0) ? wy0 * wx0 : 0.f;
  const float w01 = (vy0 && vx1) ? wy0 * wx1 : 0.f;
  const float w10 = (vy1 && vx0) ? wy1 * wx0 : 0.f;
  const float w11 = (vy1 && vx1) ? wy1 * wx1 : 0.f;
  const int i00 = y0c * 64 + x0c, i01 = y0c * 64 + x1c, i10 = y1c * 64 + x0c, i11 = y1c * 64 + x1c;
  const float* fb = f2 + (size_t)b * 32 * HW_;
  for (int c = 0; c < 32; ++c) {
    const float* fc = fb + c * HW_;
    const float v = w00 * fc[i00] + w01 * fc[i01] + w10 * fc[i10] + w11 * fc[i11];
    f2s[((size_t)n * 32 + c) * HW_ + h * 64 + w] = f2b(v);
  }
}

// ------------------------------------------------- conv1 f1-part (per b, once)
__global__ __launch_bounds__(256) void part1_kernel(
    const float* __restrict__ f1, const float* __restrict__ w1, float* __restrict__ part1)
{
  __shared__ float wl[8 * 32 * 9];
  const int b = blockIdx.z;
  const int co0 = blockIdx.y * 8;
  for (int idx = threadIdx.x; idx < 8 * 32 * 9; idx += 256) {
    const int k = idx / 288, rem = idx - k * 288;
    wl[idx] = w1[(co0 + k) * 594 + rem];
  }
  __syncthreads();
  const int wo = threadIdx.x & 63;
  const int ho = blockIdx.x * 4 + (threadIdx.x >> 6);
  float acc[8] = {};
  for (int ci = 0; ci < 32; ++ci) {
    const float* fc = f1 + ((size_t)(b * 32 + ci)) * HW_;
#pragma unroll
    for (int kh = 0; kh < 3; ++kh) {
      const int hi = ho + kh - 1;
      const bool vh = (unsigned)hi < 64u;
#pragma unroll
      for (int kw = 0; kw < 3; ++kw) {
        const int wi = wo + kw - 1;
        float v = 0.f;
        if (vh && (unsigned)wi < 64u) v = fc[hi * 64 + wi];
#pragma unroll
        for (int k = 0; k < 8; ++k) acc[k] += v * wl[(k * 32 + ci) * 9 + kh * 3 + kw];
      }
    }
  }
#pragma unroll
  for (int k = 0; k < 8; ++k)
    part1[((size_t)(b * 96 + co0 + k)) * HW_ + ho * 64 + wo] = acc[k];
}

// ------------------------------------------------------------------- conv1
__global__ __launch_bounds__(256) void conv1_kernel(
    const bf16* __restrict__ f2s, const float* __restrict__ w1, const float* __restrict__ part1,
    bf16* __restrict__ x1, float* __restrict__ stat)
{
  __shared__ float wl[8 * 34 * 9];  // stack channels 32..65
  const int n = blockIdx.z, b = n / 81, ij = n % 81;
  const float di = (float)(ij / 9) - 4.f, dj = (float)(ij % 9) - 4.f;
  const int co0 = blockIdx.y * 8;
  for (int idx = threadIdx.x; idx < 8 * 34 * 9; idx += 256) {
    const int k = idx / 306, rem = idx - k * 306;
    wl[idx] = w1[(co0 + k) * 594 + 288 + rem];
  }
  __syncthreads();
  const int wo = threadIdx.x & 63;
  const int ho = blockIdx.x * 4 + (threadIdx.x >> 6);
  float acc[8];
#pragma unroll
  for (int k = 0; k < 8; ++k)
    acc[k] = part1[((size_t)(b * 96 + co0 + k)) * HW_ + ho * 64 + wo];
  for (int ci = 0; ci < 32; ++ci) {  // f2s channels
    const bf16* fc = f2s + ((size_t)n * 32 + ci) * HW_;
#pragma unroll
    for (int kh = 0; kh < 3; ++kh) {
      const int hi = ho + kh - 1;
      const bool vh = (unsigned)hi < 64u;
#pragma unroll
      for (int kw = 0; kw < 3; ++kw) {
        const int wi = wo + kw - 1;
        float v = 0.f;
        if (vh && (unsigned)wi < 64u) v = b2f(fc[hi * 64 + wi]);
#pragma unroll
        for (int k = 0; k < 8; ++k) acc[k] += v * wl[(k * 34 + ci) * 9 + kh * 3 + kw];
      }
    }
  }
#pragma unroll
  for (int kh = 0; kh < 3; ++kh) {  // delta channels (zero-padded like the rest)
    const int hi = ho + kh - 1;
    const bool vh = (unsigned)hi < 64u;
#pragma unroll
    for (int kw = 0; kw < 3; ++kw) {
      const int wi = wo + kw - 1;
      const bool vv = vh && (unsigned)wi < 64u;
      const float v0 = vv ? di : 0.f, v1 = vv ? dj : 0.f;
#pragma unroll
      for (int k = 0; k < 8; ++k) {
        acc[k] += v0 * wl[(k * 34 + 32) * 9 + kh * 3 + kw];
        acc[k] += v1 * wl[(k * 34 + 33) * 9 + kh * 3 + kw];
      }
    }
  }
  const int lane = threadIdx.x & 63;
#pragma unroll
  for (int k = 0; k < 8; ++k) {
    const float y = acc[k];
    x1[((size_t)n * 96 + co0 + k) * HW_ + ho * 64 + wo] = f2b(y);
    float s = y, q = y * y;
#pragma unroll
    for (int o = 32; o > 0; o >>= 1) { s += __shfl_xor(s, o); q += __shfl_xor(q, o); }
    if (lane == 0) { atomicAdd(&stat[2 * (co0 + k)], s); atomicAdd(&stat[2 * (co0 + k) + 1], q); }
  }
}

// -------------------------------------------- generic 3x3 conv, BN+ReLU on read
template <int CIN, int COUT, int COT, int HIN, int WIN, int STRIDE>
__global__ __launch_bounds__(256) void conv3x3_bn(
    const bf16* __restrict__ in, const float* __restrict__ w,
    const float* __restrict__ scale, const float* __restrict__ shift,
    bf16* __restrict__ out, float* __restrict__ stat)
{
  constexpr int HO = HIN / STRIDE, WO = WIN / STRIDE;
  constexpr int ROWS = 256 / WO;
  __shared__ float wl[COT * CIN * 9];
  const int n = blockIdx.z;
  const int co0 = blockIdx.y * COT;
  for (int idx = threadIdx.x; idx < COT * CIN * 9; idx += 256)
    wl[idx] = w[co0 * CIN * 9 + idx];
  __syncthreads();
  const int wo = threadIdx.x % WO;
  const int ho = blockIdx.x * ROWS + threadIdx.x / WO;
  float acc[COT];
#pragma unroll
  for (int k = 0; k < COT; ++k) acc[k] = 0.f;
  const bf16* inN = in + (size_t)n * CIN * HIN * WIN;
  for (int ci = 0; ci < CIN; ++ci) {
    const float sc = scale[ci], sh = shift[ci];
    const bf16* inC = inN + (size_t)ci * HIN * WIN;
#pragma unroll
    for (int kh = 0; kh < 3; ++kh) {
      const int hi = ho * STRIDE + kh - 1;
      const bool vh = (unsigned)hi < (unsigned)HIN;
#pragma unroll
      for (int kw = 0; kw < 3; ++kw) {
        const int wi = wo * STRIDE + kw - 1;
        float v = 0.f;
        if (vh && (unsigned)wi < (unsigned)WIN)
          v = fmaxf(sc * b2f(inC[hi * WIN + wi]) + sh, 0.f);
#pragma unroll
        for (int k = 0; k < COT; ++k) acc[k] += v * wl[(k * CIN + ci) * 9 + kh * 3 + kw];
      }
    }
  }
  const int lane = threadIdx.x & 63;
#pragma unroll
  for (int k = 0; k < COT; ++k) {
    const float y = acc[k];
    out[(((size_t)n * COUT + co0 + k) * HO + ho) * WO + wo] = f2b(y);
    float s = y, q = y * y;
#pragma unroll
    for (int o = 32; o > 0; o >>= 1) { s += __shfl_xor(s, o); q += __shfl_xor(q, o); }
    if (lane == 0) { atomicAdd(&stat[2 * (co0 + k)], s); atomicAdd(&stat[2 * (co0 + k) + 1], q); }
  }
}

// -------------------------------------------------- transposed conv (k4 s2 p1)
__global__ __launch_bounds__(256) void deconv_kernel(
    const bf16* __restrict__ x4, const float* __restrict__ wd,
    const float* __restrict__ sc4, const float* __restrict__ sh4,
    bf16* __restrict__ xd, float* __restrict__ stat)
{
  __shared__ float wl[8 * 64 * 16];
  const int n = blockIdx.z, co0 = blockIdx.y * 8;
  for (int idx = threadIdx.x; idx < 8 * 64 * 16; idx += 256) wl[idx] = wd[co0 * 1024 + idx];
  __syncthreads();
  const int ow = threadIdx.x & 63;
  const int oh = blockIdx.x * 4 + (threadIdx.x >> 6);
  const int khp = oh & 1, kwp = ow & 1;
  float acc[8] = {};
  for (int ci = 0; ci < 64; ++ci) {
    const float s = sc4[ci], t = sh4[ci];
    const bf16* xc = x4 + ((size_t)n * 64 + ci) * 1024;
#pragma unroll
    for (int th = 0; th < 2; ++th) {
      const int kh = khp + 2 * th;
      const int ih = (oh + kh - 2) / 2;  // even numerator -> exact
      const bool vh = (unsigned)ih < 32u;
#pragma unroll
      for (int tw = 0; tw < 2; ++tw) {
        const int kw = kwp + 2 * tw;
        const int iw = (ow + kw - 2) / 2;
        float v = 0.f;
        if (vh && (unsigned)iw < 32u) v = fmaxf(s * b2f(xc[ih * 32 + iw]) + t, 0.f);
#pragma unroll
        for (int k = 0; k < 8; ++k) acc[k] += v * wl[k * 1024 + ci * 16 + kh * 4 + kw];
      }
    }
  }
  const int lane = threadIdx.x & 63;
#pragma unroll
  for (int k = 0; k < 8; ++k) {
    const float y = acc[k];
    xd[((size_t)n * 32 + co0 + k) * HW_ + oh * 64 + ow] = f2b(y);
    float s = y, q = y * y;
#pragma unroll
    for (int o = 32; o > 0; o >>= 1) { s += __shfl_xor(s, o); q += __shfl_xor(q, o); }
    if (lane == 0) { atomicAdd(&stat[2 * (co0 + k)], s); atomicAdd(&stat[2 * (co0 + k) + 1], q); }
  }
}

// ----------------------------------------------------- conv5 -> cost (fp32 out)
__global__ __launch_bounds__(256) void conv5_kernel(
    const bf16* __restrict__ xd, const float* __restrict__ w5, const float* __restrict__ b5,
    const float* __restrict__ sc, const float* __restrict__ sh, float* __restrict__ outp)
{
  __shared__ float wl[288];
  const int n = blockIdx.z, b = n / 81, dI = n % 81;
  for (int idx = threadIdx.x; idx < 288; idx += 256) wl[idx] = w5[idx];
  __syncthreads();
  const int wo = threadIdx.x & 63;
  const int ho = blockIdx.x * 4 + (threadIdx.x >> 6);
  float acc = 0.f;
  for (int ci = 0; ci < 32; ++ci) {
    const float s = sc[ci], t = sh[ci];
    const bf16* xc = xd + ((size_t)n * 32 + ci) * HW_;
#pragma unroll
    for (int kh = 0; kh < 3; ++kh) {
      const int hi = ho + kh - 1;
      const bool vh = (unsigned)hi < 64u;
#pragma unroll
      for (int kw = 0; kw < 3; ++kw) {
        const int wi = wo + kw - 1;
        float v = 0.f;
        if (vh && (unsigned)wi < 64u) v = fmaxf(s * b2f(xc[hi * 64 + wi]) + t, 0.f);
        acc += v * wl[ci * 9 + kh * 3 + kw];
      }
    }
  }
  outp[((size_t)(b * 113 + dI)) * HW_ + ho * 64 + wo] = acc + b5[0];
}

// ------------------------------------------------------- embedding 1x1 layers
__global__ __launch_bounds__(256) void e1_kernel(
    const float* __restrict__ f1, const bf16* __restrict__ f2s,
    const float* __restrict__ w, const float* __restrict__ bias, bf16* __restrict__ out)
{
  __shared__ float wl[48 * 66];
  const int n = blockIdx.z, b = n / 81, ij = n % 81;
  const float di = (float)(ij / 9) - 4.f, dj = (float)(ij % 9) - 4.f;
  for (int idx = threadIdx.x; idx < 48 * 66; idx += 256) wl[idx] = w[idx];
  __syncthreads();
  const int pix = blockIdx.x * 256 + threadIdx.x;
  const float* f1p = f1 + (size_t)b * 32 * HW_ + pix;
  const bf16* fsp = f2s + (size_t)n * 32 * HW_ + pix;
  float acc[48] = {};
  for (int ci = 0; ci < 32; ++ci) {
    const float v = f1p[ci * HW_];
#pragma unroll
    for (int k = 0; k < 48; ++k) acc[k] += v * wl[k * 66 + ci];
  }
  for (int ci = 0; ci < 32; ++ci) {
    const float v = b2f(fsp[ci * HW_]);
#pragma unroll
    for (int k = 0; k < 48; ++k) acc[k] += v * wl[k * 66 + 32 + ci];
  }
#pragma unroll
  for (int k = 0; k < 48; ++k) acc[k] += di * wl[k * 66 + 64] + dj * wl[k * 66 + 65];
  bf16* op = out + (size_t)n * 48 * HW_ + pix;
#pragma unroll
  for (int k = 0; k < 48; ++k) op[k * HW_] = f2b(fmaxf(acc[k] + bias[k], 0.f));
}

template <int CIN, int COUT, bool RELU>
__global__ __launch_bounds__(256) void pconv(
    const bf16* __restrict__ in, const float* __restrict__ w,
    const float* __restrict__ bias, bf16* __restrict__ out)
{
  __shared__ float wl[COUT * CIN];
  const int n = blockIdx.z;
  for (int idx = threadIdx.x; idx < COUT * CIN; idx += 256) wl[idx] = w[idx];
  __syncthreads();
  const int pix = blockIdx.x * 256 + threadIdx.x;
  const bf16* ip = in + (size_t)n * CIN * HW_ + pix;
  float acc[COUT];
#pragma unroll
  for (int k = 0; k < COUT; ++k) acc[k] = 0.f;
  for (int ci = 0; ci < CIN; ++ci) {
    const float v = b2f(ip[ci * HW_]);
#pragma unroll
    for (int k = 0; k < COUT; ++k) acc[k] += v * wl[k * CIN + ci];
  }
  bf16* op = out + (size_t)n * COUT * HW_ + pix;
#pragma unroll
  for (int k = 0; k < COUT; ++k) {
    float y = acc[k] + bias[k];
    if (RELU) y = fmaxf(y, 0.f);
    op[k * HW_] = f2b(y);
  }
}

// ----------------------------------------------------------- BN finalize
__global__ void bnfin_kernel(float* __restrict__ statL, const float* __restrict__ g,
                             const float* __restrict__ bt, int C, float invCnt)
{
  const int c = threadIdx.x;
  if (c < C) {
    const float m = statL[2 * c] * invCnt;
    const float var = statL[2 * c + 1] * invCnt - m * m;
    const float sc = g[c] * rsqrtf(var + 1e-5f);
    statL[256 + c] = sc;
    statL[384 + c] = bt[c] - m * sc;
  }
}

// ----------------------------------------------------- dapw-matmul + softmax
__global__ __launch_bounds__(64) void softmax_kernel(
    const float* __restrict__ outp, const float* __restrict__ dapw, float* __restrict__ score)
{
  __shared__ float cb[64 * 81];
  __shared__ float sb[64 * 81];
  const int t = threadIdx.x;
  const int gid = blockIdx.x * 64 + t;
  const int b = gid >> 12, hw = gid & 4095;
  for (int d = 0; d < 81; ++d)
    cb[t * 81 + d] = outp[((size_t)(b * 113 + d)) * HW_ + hw];
  float smax = -1e30f;
  for (int o = 0; o < 81; ++o) {
    float s = 0.f;
    const float* dr = dapw + o * 81;
    for (int d = 0; d < 81; ++d) s += dr[d] * cb[t * 81 + d];
    sb[t * 81 + o] = s;
    smax = fmaxf(smax, s);
  }
  float sum = 0.f;
  for (int o = 0; o < 81; ++o) {
    const float e = __expf(sb[t * 81 + o] - smax);
    sb[t * 81 + o] = e;
    sum += e;
  }
  const float inv = 1.f / sum;
  for (int o = 0; o < 81; ++o)
    score[((size_t)(b * 81 + o)) * HW_ + hw] = sb[t * 81 + o] * inv;
}

// --------------------------------------------------- weighted embedding reduce
__global__ __launch_bounds__(256) void emb_kernel(
    const float* __restrict__ score, const bf16* __restrict__ e3, float* __restrict__ outp)
{
  const int idx = blockIdx.x * 256 + threadIdx.x;  // 2*32*4096 total
  const int b = idx >> 17, r = idx & 131071, m = r >> 12, hw = r & 4095;
  float acc = 0.f;
  for (int d = 0; d < 81; ++d) {
    const float sc = score[((size_t)(b * 81 + d)) * HW_ + hw];
    acc += sc * b2f(e3[(((size_t)(b * 81 + d)) * 32 + m) * HW_ + hw]);
  }
  outp[((size_t)(b * 113 + 81 + m)) * HW_ + hw] = acc;
}

// ======================================================================
extern "C" void kernel_launch(void* const* d_in, const int* in_sizes, int n_in,
                              void* d_out, int out_size, void* d_ws, size_t ws_size,
                              hipStream_t stream) {
  const float* f1    = (const float*)d_in[0];
  const float* f2    = (const float*)d_in[1];
  const float* coords= (const float*)d_in[2];
  const float* w1    = (const float*)d_in[3];
  const float* g1    = (const float*)d_in[4];
  const float* bb1   = (const float*)d_in[5];
  const float* w2    = (const float*)d_in[6];
  const float* g2    = (const float*)d_in[7];
  const float* bb2   = (const float*)d_in[8];
  const float* w3    = (const float*)d_in[9];
  const float* g3    = (const float*)d_in[10];
  const float* bb3   = (const float*)d_in[11];
  const float* w4    = (const float*)d_in[12];
  const float* g4    = (const float*)d_in[13];
  const float* bb4   = (const float*)d_in[14];
  const float* wdcv  = (const float*)d_in[15];
  const float* gd    = (const float*)d_in[16];
  const float* bbd   = (const float*)d_in[17];
  const float* w5    = (const float*)d_in[18];
  const float* b5    = (const float*)d_in[19];
  const float* e1w   = (const float*)d_in[20];
  const float* e1bi  = (const float*)d_in[21];
  const float* e2w   = (const float*)d_in[22];
  const float* e2bi  = (const float*)d_in[23];
  const float* e3w   = (const float*)d_in[24];
  const float* e3bi  = (const float*)d_in[25];
  const float* dapw  = (const float*)d_in[26];
  float* out = (float*)d_out;
  char* ws = (char*)d_ws;

  bf16* f2s = (bf16*)(ws + OFF_F2S);
  bf16* be1 = (bf16*)(ws + OFF_E1);
  bf16* be2 = (bf16*)(ws + OFF_E2);
  bf16* be3 = (bf16*)(ws + OFF_E3);
  bf16* x1  = (bf16*)(ws + OFF_X1);
  bf16* x2  = (bf16*)(ws + OFF_X2);
  bf16* x3  = (bf16*)(ws + OFF_X3);
  bf16* x4  = (bf16*)(ws + OFF_X4);
  bf16* xd  = (bf16*)(ws + OFF_XD);
  float* score = (float*)(ws + OFF_SCORE);
  float* stats = (float*)(ws + OFF_STATS);
  float* p1    = (float*)(ws + OFF_P1);

  // zero BN-stat accumulators (atomics) every call
  hipMemsetAsync(stats, 0, 2560 * sizeof(float), stream);

  // build sampled f2 volume
  sample_kernel<<<dim3(16, 1, 162), 256, 0, stream>>>(f2, coords, f2s);

  // embedding branch first (frees f2s-adjacent arena for matching branch)
  e1_kernel<<<dim3(16, 1, 162), 256, 0, stream>>>(f1, f2s, e1w, e1bi, be1);
  pconv<48, 64, true ><<<dim3(16, 1, 162), 256, 0, stream>>>(be1, e2w, e2bi, be2);
  pconv<64, 32, false><<<dim3(16, 1, 162), 256, 0, stream>>>(be2, e3w, e3bi, be3);

  // matching branch
  part1_kernel<<<dim3(16, 12, 2), 256, 0, stream>>>(f1, w1, p1);
  conv1_kernel<<<dim3(16, 12, 162), 256, 0, stream>>>(f2s, w1, p1, x1, stats);
  bnfin_kernel<<<1, 128, 0, stream>>>(stats, g1, bb1, 96, 1.f / 663552.f);
  conv3x3_bn<96, 128, 8, 64, 64, 2><<<dim3(4, 16, 162), 256, 0, stream>>>(
      x1, w2, stats + 256, stats + 384, x2, stats + 512);
  bnfin_kernel<<<1, 128, 0, stream>>>(stats + 512, g2, bb2, 128, 1.f / 165888.f);
  conv3x3_bn<128, 128, 8, 32, 32, 1><<<dim3(4, 16, 162), 256, 0, stream>>>(
      x2, w3, stats + 768, stats + 896, x3, stats + 1024);
  bnfin_kernel<<<1, 128, 0, stream>>>(stats + 1024, g3, bb3, 128, 1.f / 165888.f);
  conv3x3_bn<128, 64, 8, 32, 32, 1><<<dim3(4, 8, 162), 256, 0, stream>>>(
      x3, w4, stats + 1280, stats + 1408, x4, stats + 1536);
  bnfin_kernel<<<1, 128, 0, stream>>>(stats + 1536, g4, bb4, 64, 1.f / 165888.f);
  deconv_kernel<<<dim3(16, 4, 162), 256, 0, stream>>>(
      x4, wdcv, stats + 1792, stats + 1920, xd, stats + 2048);
  bnfin_kernel<<<1, 128, 0, stream>>>(stats + 2048, gd, bbd, 32, 1.f / 663552.f);
  conv5_kernel<<<dim3(16, 1, 162), 256, 0, stream>>>(
      xd, w5, b5, stats + 2304, stats + 2432, out);

  // DAP softmax + embedding reduction
  softmax_kernel<<<128, 64, 0, stream>>>(out, dapw, score);
  emb_kernel<<<1024, 256, 0, stream>>>(score, be3, out);

  (void)in_sizes; (void)n_in; (void)out_size; (void)ws_size;
}

// Round 2
// 1222.998 us; speedup vs baseline: 12.1709x; 12.1709x over previous
//
#include <hip/hip_runtime.h>
#include <hip/hip_bf16.h>

using bf16 = __hip_bfloat16;
typedef short  s8v   __attribute__((ext_vector_type(8)));
typedef float  f32x4 __attribute__((ext_vector_type(4)));

#define DEVINL __device__ __forceinline__

DEVINL float b2f_bits(unsigned short u) { return __uint_as_float(((unsigned)u) << 16); }
DEVINL unsigned short f2b_bits(float f) {
  return __builtin_bit_cast(unsigned short, __float2bfloat16(f));
}
DEVINL bf16 f2b(float v) { return __float2bfloat16(v); }

// ---------------------------------------------------------------- arena
static constexpr size_t OFF_SA    = 0;           // f1 packed  [2][4096][32] bf16
static constexpr size_t OFF_F2S   = 524288;      // f2 sampled [162][4096][32] bf16 (dead after conv1; reused x2/x4/score)
static constexpr size_t OFF_E1    = 42991616;    // e1out [162][4096][48] (phase B only)
static constexpr size_t OFF_E2    = 106692608;   // e2out [162][4096][64] (phase B only)
static constexpr size_t OFF_E3    = 42991616;    // e3out [162][4096][32] (reuse E1; alive to end)
static constexpr size_t OFF_X1    = 85458944;    // x1 [162][4096][96] (dead after conv2)
static constexpr size_t OFF_X2    = 524288;      // x2 [162][1024][128]
static constexpr size_t OFF_X3    = 85458944;    // x3 [162][1024][128]
static constexpr size_t OFF_X4    = 524288;      // x4 [162][1024][64]
static constexpr size_t OFF_XD    = 127926272;   // xd [162][4096][32]
static constexpr size_t OFF_SCORE = 524288;      // f32 [2][81][4096]
static constexpr size_t OFF_STATS = 212860928;   // f32 2560
static constexpr size_t OFF_WC1   = 212871168;
static constexpr size_t OFF_WC2   = 212981760;
static constexpr size_t OFF_WC3   = 213202944;
static constexpr size_t OFF_WC4   = 213497856;
static constexpr size_t OFF_WDC   = 213645312;
static constexpr size_t OFF_WC5   = 213710848;
static constexpr size_t OFF_WE1   = 213720064;
static constexpr size_t OFF_WE2   = 213726208;
static constexpr size_t OFF_WE3   = 213734400;
static constexpr size_t OFF_DT1   = 213738496;
static constexpr size_t OFF_DTE   = 213745408;

// ---------------------------------------------------------------- prepack
// dst[t][co][k] = (co<COr && k<CINr) ? src[(co*CINsrc + k)*TAPS + t] : 0
__global__ void prepack(const float* __restrict__ src, bf16* __restrict__ dst,
                        int COr, int COP, int CINr, int CINsrc, int KP, int TAPS) {
  const int idx = blockIdx.x * 256 + threadIdx.x;
  const int total = TAPS * COP * KP;
  if (idx >= total) return;
  const int k = idx % KP;
  const int r = idx / KP;
  const int co = r % COP;
  const int t = r / COP;
  float v = 0.f;
  if (co < COr && k < CINr) v = src[((size_t)co * CINsrc + k) * TAPS + t];
  dst[idx] = f2b(v);
}

// delta border table for conv1: dtab[co][rc*3+cc][2] = sum of w1[co][64+c][kh][kw] over valid taps
__global__ void dtab1_kernel(const float* __restrict__ w1, float* __restrict__ dtab) {
  const int idx = blockIdx.x * 256 + threadIdx.x;  // 96*9*2
  if (idx >= 96 * 9 * 2) return;
  const int c = idx & 1;
  const int r = idx >> 1;
  const int pat = r % 9;
  const int co = r / 9;
  const int rc = pat / 3, cc = pat % 3;
  const int kh0 = (rc == 0) ? 1 : 0, kh1 = (rc == 2) ? 1 : 2;
  const int kw0 = (cc == 0) ? 1 : 0, kw1 = (cc == 2) ? 1 : 2;
  float s = 0.f;
  for (int kh = kh0; kh <= kh1; ++kh)
    for (int kw = kw0; kw <= kw1; ++kw)
      s += w1[((size_t)(co * 66 + 64 + c) * 3 + kh) * 3 + kw];
  dtab[(co * 9 + pat) * 2 + c] = s;
}

__global__ void dtabE_kernel(const float* __restrict__ e1w, float* __restrict__ dtE) {
  const int co = threadIdx.x;
  if (co < 48) {
    dtE[co * 2 + 0] = e1w[co * 66 + 64];
    dtE[co * 2 + 1] = e1w[co * 66 + 65];
  }
}

// ---------------------------------------------------------------- input builders
__global__ __launch_bounds__(256) void packf1(const float* __restrict__ f1, bf16* __restrict__ sA) {
  const int gid = blockIdx.x * 256 + threadIdx.x;  // 2*4096
  const int b = gid >> 12, pix = gid & 4095;
  unsigned words[16];
#pragma unroll
  for (int c = 0; c < 32; c += 2) {
    const float v0 = f1[((size_t)(b * 32 + c)) * 4096 + pix];
    const float v1 = f1[((size_t)(b * 32 + c + 1)) * 4096 + pix];
    words[c >> 1] = (unsigned)f2b_bits(v0) | ((unsigned)f2b_bits(v1) << 16);
  }
  uint4* dst = (uint4*)(sA + (size_t)gid * 32);
#pragma unroll
  for (int i = 0; i < 4; ++i)
    dst[i] = make_uint4(words[4 * i], words[4 * i + 1], words[4 * i + 2], words[4 * i + 3]);
}

__global__ __launch_bounds__(256) void sample2(const float* __restrict__ f2,
                                               const float* __restrict__ coords,
                                               bf16* __restrict__ f2s) {
  const int gid = blockIdx.x * 256 + threadIdx.x;  // 162*4096
  const int n = gid >> 12, pix = gid & 4095;
  const int b = n / 81, ij = n - b * 81;
  const float di = (float)(ij / 9) - 4.f, dj = (float)(ij % 9) - 4.f;
  const float x = coords[((size_t)(b * 2 + 0)) * 4096 + pix] + di;
  const float y = coords[((size_t)(b * 2 + 1)) * 4096 + pix] + dj;
  const float x0f = floorf(x), y0f = floorf(y);
  const int x0 = (int)x0f, y0 = (int)y0f;
  const float wx1 = x - x0f, wx0 = 1.f - wx1;
  const float wy1 = y - y0f, wy0 = 1.f - wy1;
  const bool vx0 = (unsigned)x0 < 64u, vx1 = (unsigned)(x0 + 1) < 64u;
  const bool vy0 = (unsigned)y0 < 64u, vy1 = (unsigned)(y0 + 1) < 64u;
  const int x0c = min(max(x0, 0), 63), x1c = min(max(x0 + 1, 0), 63);
  const int y0c = min(max(y0, 0), 63), y1c = min(max(y0 + 1, 0), 63);
  const float w00 = (vy0 && vx0) ? wy0 * wx0 : 0.f;
  const float w01 = (vy0 && vx1) ? wy0 * wx1 : 0.f;
  const float w10 = (vy1 && vx0) ? wy1 * wx0 : 0.f;
  const float w11 = (vy1 && vx1) ? wy1 * wx1 : 0.f;
  const int i00 = y0c * 64 + x0c, i01 = y0c * 64 + x1c;
  const int i10 = y1c * 64 + x0c, i11 = y1c * 64 + x1c;
  const float* fb = f2 + (size_t)b * 32 * 4096;
  unsigned words[16];
#pragma unroll
  for (int c = 0; c < 32; c += 2) {
    const float* fc0 = fb + (size_t)c * 4096;
    const float* fc1 = fb + (size_t)(c + 1) * 4096;
    const float v0 = w00 * fc0[i00] + w01 * fc0[i01] + w10 * fc0[i10] + w11 * fc0[i11];
    const float v1 = w00 * fc1[i00] + w01 * fc1[i01] + w10 * fc1[i10] + w11 * fc1[i11];
    words[c >> 1] = (unsigned)f2b_bits(v0) | ((unsigned)f2b_bits(v1) << 16);
  }
  uint4* dst = (uint4*)(f2s + (size_t)gid * 32);
#pragma unroll
  for (int i = 0; i < 4; ++i)
    dst[i] = make_uint4(words[4 * i], words[4 * i + 1], words[4 * i + 2], words[4 * i + 3]);
}

// ---------------------------------------------------------------- MFMA conv template
// GEOM: 0 = 3x3 stride1 | 1 = 3x3 stride2 (in 64 -> out 32) | 2 = deconv parity | 3 = 1x1
// EPI : 0 = raw store + BN stats | 1 = bias+relu | 2 = bias | 3 = conv5 cost f32
// Layouts: activations channel-last [n][pix][G] bf16; weights [tap][COP][KP] bf16.
template <int GEOM, int EPI, bool DUAL, int G, int KP, int COP, int COB, int MFR,
          int IMGO, int IMGI, int PIXROWS, int WPIX, bool DELTA>
__global__ __launch_bounds__(256) void mconv(
    const bf16* __restrict__ src1, const bf16* __restrict__ src0,
    const bf16* __restrict__ wp, const float* __restrict__ bias,
    const float* __restrict__ dtab, float* __restrict__ statL,
    bf16* __restrict__ outB, float* __restrict__ outF) {
  constexpr int TAPS  = (GEOM == 2) ? 4 : (GEOM == 3) ? 1 : 9;
  constexpr int TR    = (GEOM == 1) ? (2 * PIXROWS + 1) : (GEOM == 3) ? PIXROWS : (PIXROWS + 2);
  constexpr int TC    = (GEOM == 1) ? 65 : (GEOM == 3) ? IMGI : (IMGI + 2);
  constexpr int NSLOT = TR * TC;
  constexpr int NCH   = KP / 32;
  constexpr int NPIXI = IMGI * IMGI;
  constexpr int NPIXO = (GEOM == 2) ? 4096 : IMGO * IMGO;

  __shared__ bf16 lds[NSLOT * 40];

  const int tid = threadIdx.x;
  const int wid = tid >> 6, lane = tid & 63, lg = lane >> 4, ln = lane & 15;
  const int n = blockIdx.z, b = n / 81, ij = n - b * 81;
  const int r0 = blockIdx.x * PIXROWS;
  const int qq = (GEOM == 2) ? (int)(blockIdx.y >> 1) : 0;
  const int pp = (GEOM == 2) ? (int)(blockIdx.y & 1) : 0;
  const int co0 = (GEOM == 2) ? 0 : (int)blockIdx.y * (MFR * 16);

  f32x4 acc[MFR][WPIX];
#pragma unroll
  for (int mf = 0; mf < MFR; ++mf)
#pragma unroll
    for (int pf = 0; pf < WPIX; ++pf) acc[mf][pf] = (f32x4){0.f, 0.f, 0.f, 0.f};

  for (int ch = 0; ch < NCH; ++ch) {
    const int k0 = ch * 32;
    // ---- stage 32-ci slab, channel-contiguous, zero-filled
    for (int idx = tid; idx < NSLOT * 4; idx += 256) {
      const int s = idx >> 2, ci8 = idx & 3;
      const int rs = s / TC, cs = s - rs * TC;
      int ir, ic;
      if (GEOM == 1)      { ir = 2 * r0 - 1 + rs; ic = (cs < 32) ? 2 * cs : 2 * (cs - 32) - 1; }
      else if (GEOM == 3) { ir = r0 + rs;         ic = cs; }
      else                { ir = r0 - 1 + rs;     ic = cs - 1; }
      const int gci = k0 + ci8 * 8;
      s8v v = (s8v){0, 0, 0, 0, 0, 0, 0, 0};
      const bool okp = ((unsigned)ir < (unsigned)IMGI) && ((unsigned)ic < (unsigned)IMGI);
      if (DUAL) {
        if (okp) {
          if (gci < 32)
            v = *(const s8v*)(src0 + (((size_t)b * NPIXI + ir * IMGI + ic) * 32 + gci));
          else if (gci < 64)
            v = *(const s8v*)(src1 + (((size_t)n * NPIXI + ir * IMGI + ic) * 32 + (gci - 32)));
        }
      } else {
        if (okp && gci < G)
          v = *(const s8v*)(src1 + (((size_t)n * NPIXI + ir * IMGI + ic) * G + gci));
      }
      *(s8v*)(&lds[s * 40 + ci8 * 8]) = v;
    }
    __syncthreads();
    // ---- taps x MFMA
    for (int t = 0; t < TAPS; ++t) {
      int dh, dw, wt, kh = 0, kw = 0;
      if (GEOM == 2) {
        dh = qq + (t >> 1) - 1; dw = pp + (t & 1) - 1;
        wt = (qq + 2 * (t >> 1)) * 4 + (pp + 2 * (t & 1));
      } else if (GEOM == 3) { dh = 0; dw = 0; wt = 0; }
      else { kh = t / 3; kw = t % 3; dh = kh - 1; dw = kw - 1; wt = t; }
      s8v afr[MFR];
#pragma unroll
      for (int mf = 0; mf < MFR; ++mf)
        afr[mf] = *(const s8v*)(wp + ((size_t)(wt * COP + co0 + mf * 16 + ln)) * KP + k0 + lg * 8);
#pragma unroll
      for (int pf = 0; pf < WPIX; ++pf) {
        const int pl = wid * (WPIX * 16) + pf * 16 + ln;
        const int rL = pl / IMGO, c = pl - rL * IMGO;
        int slot;
        if (GEOM == 1)      slot = (2 * rL + kh) * 65 + ((kw == 1) ? c : (32 + c + (kw >> 1)));
        else if (GEOM == 3) slot = rL * TC + c;
        else                slot = (rL + dh + 1) * TC + (c + dw + 1);
        const s8v bfr = *(const s8v*)(&lds[slot * 40 + lg * 8]);
#pragma unroll
        for (int mf = 0; mf < MFR; ++mf)
          acc[mf][pf] = __builtin_amdgcn_mfma_f32_16x16x32_bf16(afr[mf], bfr, acc[mf][pf], 0, 0, 0);
      }
    }
    __syncthreads();
  }

  const float di = (float)(ij / 9) - 4.f, dj = (float)(ij % 9) - 4.f;

  if constexpr (EPI == 3) {
    if (lg == 0) {
#pragma unroll
      for (int pf = 0; pf < WPIX; ++pf) {
        const int pl = wid * (WPIX * 16) + pf * 16 + ln;
        const int rL = pl / IMGO, c = pl - rL * IMGO;
        const int opix = (r0 + rL) * IMGO + c;
        outF[((size_t)(b * 113 + ij)) * 4096 + opix] = acc[0][pf][0] + bias[0];
      }
    }
    return;
  } else {
#pragma unroll
    for (int mf = 0; mf < MFR; ++mf) {
#pragma unroll
      for (int pf = 0; pf < WPIX; ++pf) {
        const int pl = wid * (WPIX * 16) + pf * 16 + ln;
        const int rL = pl / IMGO, c = pl - rL * IMGO;
        int opix;
        if constexpr (GEOM == 2) opix = (2 * (r0 + rL) + qq) * 64 + 2 * c + pp;
        else opix = (r0 + rL) * IMGO + c;
        if constexpr (DELTA && EPI == 0) {
          const int oh = r0 + rL;
          const int rc = (oh == 0) ? 0 : ((oh == IMGO - 1) ? 2 : 1);
          const int cc = (c == 0) ? 0 : ((c == IMGO - 1) ? 2 : 1);
#pragma unroll
          for (int rg = 0; rg < 4; ++rg) {
            const int co = co0 + mf * 16 + lg * 4 + rg;
            acc[mf][pf][rg] += di * dtab[(co * 9 + rc * 3 + cc) * 2 + 0] +
                               dj * dtab[(co * 9 + rc * 3 + cc) * 2 + 1];
          }
        }
        if constexpr (DELTA && EPI == 1) {
#pragma unroll
          for (int rg = 0; rg < 4; ++rg) {
            const int co = co0 + mf * 16 + lg * 4 + rg;
            acc[mf][pf][rg] += di * dtab[co * 2] + dj * dtab[co * 2 + 1];
          }
        }
        if constexpr (EPI == 1 || EPI == 2) {
          const float4 bv = *(const float4*)(bias + co0 + mf * 16 + lg * 4);
          acc[mf][pf][0] += bv.x; acc[mf][pf][1] += bv.y;
          acc[mf][pf][2] += bv.z; acc[mf][pf][3] += bv.w;
          if constexpr (EPI == 1) {
#pragma unroll
            for (int rg = 0; rg < 4; ++rg) acc[mf][pf][rg] = fmaxf(acc[mf][pf][rg], 0.f);
          }
        }
        ushort4 st;
        st.x = f2b_bits(acc[mf][pf][0]); st.y = f2b_bits(acc[mf][pf][1]);
        st.z = f2b_bits(acc[mf][pf][2]); st.w = f2b_bits(acc[mf][pf][3]);
        *reinterpret_cast<ushort4*>(outB + ((size_t)n * NPIXO + opix) * COB + co0 + mf * 16 + lg * 4) = st;
      }
    }
    if constexpr (EPI == 0) {
      float* sl = (float*)lds;  // safe: synced after last tap loop
#pragma unroll
      for (int mf = 0; mf < MFR; ++mf) {
#pragma unroll
        for (int rg = 0; rg < 4; ++rg) {
          float s = 0.f, q2 = 0.f;
#pragma unroll
          for (int pf = 0; pf < WPIX; ++pf) {
            const float v = acc[mf][pf][rg];
            s += v; q2 += v * v;
          }
#pragma unroll
          for (int o = 1; o < 16; o <<= 1) { s += __shfl_xor(s, o); q2 += __shfl_xor(q2, o); }
          if (ln == 0) {
            const int cl = mf * 16 + lg * 4 + rg;
            sl[(wid * MFR * 16 + cl) * 2 + 0] = s;
            sl[(wid * MFR * 16 + cl) * 2 + 1] = q2;
          }
        }
      }
      __syncthreads();
      for (int i = tid; i < MFR * 16 * 2; i += 256) {
        const int cl = i >> 1, stt = i & 1;
        float tot = 0.f;
#pragma unroll
        for (int w = 0; w < 4; ++w) tot += sl[(w * MFR * 16 + cl) * 2 + stt];
        atomicAdd(&statL[2 * (co0 + cl) + stt], tot);
      }
    }
  }
}

// ---------------------------------------------------------------- BN finalize
__global__ void bnfin_kernel(float* __restrict__ statL, const float* __restrict__ g,
                             const float* __restrict__ bt, int C, float invCnt) {
  const int c = threadIdx.x;
  if (c < C) {
    const float m = statL[2 * c] * invCnt;
    const float var = statL[2 * c + 1] * invCnt - m * m;
    const float sc = g[c] * rsqrtf(var + 1e-5f);
    statL[256 + c] = sc;
    statL[384 + c] = bt[c] - m * sc;
  }
}

// ---------------------------------------------------------------- in-place BN+ReLU
template <int G8>
__global__ __launch_bounds__(256) void norm_ip(bf16* __restrict__ x,
                                               const float* __restrict__ statL, long nch) {
  for (long i = (long)blockIdx.x * 256 + threadIdx.x; i < nch; i += (long)gridDim.x * 256) {
    const int ci8 = (int)(i % G8);
    s8v v = *(s8v*)(x + i * 8);
    const f32x4 scA = *(const f32x4*)(statL + 256 + ci8 * 8);
    const f32x4 scB = *(const f32x4*)(statL + 256 + ci8 * 8 + 4);
    const f32x4 shA = *(const f32x4*)(statL + 384 + ci8 * 8);
    const f32x4 shB = *(const f32x4*)(statL + 384 + ci8 * 8 + 4);
    s8v o;
#pragma unroll
    for (int j = 0; j < 8; ++j) {
      const float sc = (j < 4) ? scA[j] : scB[j - 4];
      const float sh = (j < 4) ? shA[j] : shB[j - 4];
      const float f = fmaxf(b2f_bits((unsigned short)v[j]) * sc + sh, 0.f);
      o[j] = (short)f2b_bits(f);
    }
    *(s8v*)(x + i * 8) = o;
  }
}

// ---------------------------------------------------------------- DAP softmax
__global__ __launch_bounds__(64) void softmax_kernel(
    const float* __restrict__ outp, const float* __restrict__ dapw, float* __restrict__ score) {
  __shared__ float cb[64 * 81];
  __shared__ float sb[64 * 81];
  const int t = threadIdx.x;
  const int gid = blockIdx.x * 64 + t;
  const int b = gid >> 12, hw = gid & 4095;
  for (int d = 0; d < 81; ++d)
    cb[t * 81 + d] = outp[((size_t)(b * 113 + d)) * 4096 + hw];
  float smax = -1e30f;
  for (int o = 0; o < 81; ++o) {
    float s = 0.f;
    const float* dr = dapw + o * 81;
    for (int d = 0; d < 81; ++d) s += dr[d] * cb[t * 81 + d];
    sb[t * 81 + o] = s;
    smax = fmaxf(smax, s);
  }
  float sum = 0.f;
  for (int o = 0; o < 81; ++o) {
    const float e = __expf(sb[t * 81 + o] - smax);
    sb[t * 81 + o] = e;
    sum += e;
  }
  const float inv = 1.f / sum;
  for (int o = 0; o < 81; ++o)
    score[((size_t)(b * 81 + o)) * 4096 + hw] = sb[t * 81 + o] * inv;
}

// ---------------------------------------------------------------- emb reduce
__global__ __launch_bounds__(256) void emb_kernel(
    const float* __restrict__ score, const bf16* __restrict__ e3, float* __restrict__ outp) {
  const int idx = blockIdx.x * 256 + threadIdx.x;  // 2*32*4096
  const int b = idx >> 17, r = idx & 131071, m = r >> 12, hw = r & 4095;
  float acc = 0.f;
  for (int d = 0; d < 81; ++d) {
    const float sc = score[((size_t)(b * 81 + d)) * 4096 + hw];
    acc += sc * b2f_bits(__builtin_bit_cast(unsigned short,
              e3[(((size_t)(b * 81 + d)) * 4096 + hw) * 32 + m]));
  }
  outp[((size_t)(b * 113 + 81 + m)) * 4096 + hw] = acc;
}

// ======================================================================
extern "C" void kernel_launch(void* const* d_in, const int* in_sizes, int n_in,
                              void* d_out, int out_size, void* d_ws, size_t ws_size,
                              hipStream_t stream) {
  const float* f1     = (const float*)d_in[0];
  const float* f2     = (const float*)d_in[1];
  const float* coords = (const float*)d_in[2];
  const float* w1     = (const float*)d_in[3];
  const float* g1     = (const float*)d_in[4];
  const float* bb1    = (const float*)d_in[5];
  const float* w2     = (const float*)d_in[6];
  const float* g2     = (const float*)d_in[7];
  const float* bb2    = (const float*)d_in[8];
  const float* w3     = (const float*)d_in[9];
  const float* g3     = (const float*)d_in[10];
  const float* bb3    = (const float*)d_in[11];
  const float* w4     = (const float*)d_in[12];
  const float* g4     = (const float*)d_in[13];
  const float* bb4    = (const float*)d_in[14];
  const float* wdcv   = (const float*)d_in[15];
  const float* gd     = (const float*)d_in[16];
  const float* bbd    = (const float*)d_in[17];
  const float* w5     = (const float*)d_in[18];
  const float* b5     = (const float*)d_in[19];
  const float* e1w    = (const float*)d_in[20];
  const float* e1bi   = (const float*)d_in[21];
  const float* e2w    = (const float*)d_in[22];
  const float* e2bi   = (const float*)d_in[23];
  const float* e3w    = (const float*)d_in[24];
  const float* e3bi   = (const float*)d_in[25];
  const float* dapw   = (const float*)d_in[26];
  float* out = (float*)d_out;
  char* ws = (char*)d_ws;

  bf16* sA  = (bf16*)(ws + OFF_SA);
  bf16* f2s = (bf16*)(ws + OFF_F2S);
  bf16* be1 = (bf16*)(ws + OFF_E1);
  bf16* be2 = (bf16*)(ws + OFF_E2);
  bf16* be3 = (bf16*)(ws + OFF_E3);
  bf16* x1  = (bf16*)(ws + OFF_X1);
  bf16* x2  = (bf16*)(ws + OFF_X2);
  bf16* x3  = (bf16*)(ws + OFF_X3);
  bf16* x4  = (bf16*)(ws + OFF_X4);
  bf16* xd  = (bf16*)(ws + OFF_XD);
  float* score = (float*)(ws + OFF_SCORE);
  float* stats = (float*)(ws + OFF_STATS);
  bf16* wc1 = (bf16*)(ws + OFF_WC1);
  bf16* wc2 = (bf16*)(ws + OFF_WC2);
  bf16* wc3 = (bf16*)(ws + OFF_WC3);
  bf16* wc4 = (bf16*)(ws + OFF_WC4);
  bf16* wdc = (bf16*)(ws + OFF_WDC);
  bf16* wc5 = (bf16*)(ws + OFF_WC5);
  bf16* we1 = (bf16*)(ws + OFF_WE1);
  bf16* we2 = (bf16*)(ws + OFF_WE2);
  bf16* we3 = (bf16*)(ws + OFF_WE3);
  float* dt1 = (float*)(ws + OFF_DT1);
  float* dtE = (float*)(ws + OFF_DTE);

  hipMemsetAsync(stats, 0, 2560 * sizeof(float), stream);

  // weight prepacks
  prepack<<<216, 256, 0, stream>>>(w1,   wc1, 96, 96, 64, 66, 64, 9);
  prepack<<<432, 256, 0, stream>>>(w2,   wc2, 128, 128, 96, 96, 96, 9);
  prepack<<<576, 256, 0, stream>>>(w3,   wc3, 128, 128, 128, 128, 128, 9);
  prepack<<<288, 256, 0, stream>>>(w4,   wc4, 64, 64, 128, 128, 128, 9);
  prepack<<<128, 256, 0, stream>>>(wdcv, wdc, 32, 32, 64, 64, 64, 16);
  prepack<<<18,  256, 0, stream>>>(w5,   wc5, 1, 16, 32, 32, 32, 9);
  prepack<<<12,  256, 0, stream>>>(e1w,  we1, 48, 48, 64, 66, 64, 1);
  prepack<<<16,  256, 0, stream>>>(e2w,  we2, 64, 64, 48, 48, 64, 1);
  prepack<<<8,   256, 0, stream>>>(e3w,  we3, 32, 32, 64, 64, 64, 1);
  dtab1_kernel<<<7, 256, 0, stream>>>(w1, dt1);
  dtabE_kernel<<<1, 96, 0, stream>>>(e1w, dtE);

  // inputs
  packf1<<<32, 256, 0, stream>>>(f1, sA);
  sample2<<<2592, 256, 0, stream>>>(f2, coords, f2s);

  // embedding branch (frees arena for matching branch)
  mconv<3, 1, true, 32, 64, 48, 48, 3, 64, 64, 4, 4, true>
      <<<dim3(16, 1, 162), 256, 0, stream>>>(f2s, sA, we1, e1bi, dtE, nullptr, be1, nullptr);
  mconv<3, 1, false, 48, 64, 64, 64, 4, 64, 64, 4, 4, false>
      <<<dim3(16, 1, 162), 256, 0, stream>>>(be1, nullptr, we2, e2bi, nullptr, nullptr, be2, nullptr);
  mconv<3, 2, false, 64, 64, 32, 32, 2, 64, 64, 4, 4, false>
      <<<dim3(16, 1, 162), 256, 0, stream>>>(be2, nullptr, we3, e3bi, nullptr, nullptr, be3, nullptr);

  // matching branch
  mconv<0, 0, true, 32, 64, 96, 96, 6, 64, 64, 4, 4, true>
      <<<dim3(16, 1, 162), 256, 0, stream>>>(f2s, sA, wc1, nullptr, dt1, stats + 0, x1, nullptr);
  bnfin_kernel<<<1, 128, 0, stream>>>(stats + 0, g1, bb1, 96, 1.f / 663552.f);
  norm_ip<12><<<2048, 256, 0, stream>>>(x1, stats + 0, 7962624L);

  mconv<1, 0, false, 96, 96, 128, 128, 4, 32, 64, 4, 2, false>
      <<<dim3(8, 2, 162), 256, 0, stream>>>(x1, nullptr, wc2, nullptr, nullptr, stats + 512, x2, nullptr);
  bnfin_kernel<<<1, 128, 0, stream>>>(stats + 512, g2, bb2, 128, 1.f / 165888.f);
  norm_ip<16><<<2048, 256, 0, stream>>>(x2, stats + 512, 2654208L);

  mconv<0, 0, false, 128, 128, 128, 128, 4, 32, 32, 8, 4, false>
      <<<dim3(4, 2, 162), 256, 0, stream>>>(x2, nullptr, wc3, nullptr, nullptr, stats + 1024, x3, nullptr);
  bnfin_kernel<<<1, 128, 0, stream>>>(stats + 1024, g3, bb3, 128, 1.f / 165888.f);
  norm_ip<16><<<2048, 256, 0, stream>>>(x3, stats + 1024, 2654208L);

  mconv<0, 0, false, 128, 128, 64, 64, 4, 32, 32, 8, 4, false>
      <<<dim3(4, 1, 162), 256, 0, stream>>>(x3, nullptr, wc4, nullptr, nullptr, stats + 1536, x4, nullptr);
  bnfin_kernel<<<1, 128, 0, stream>>>(stats + 1536, g4, bb4, 64, 1.f / 165888.f);
  norm_ip<8><<<2048, 256, 0, stream>>>(x4, stats + 1536, 1327104L);

  mconv<2, 0, false, 64, 64, 32, 32, 2, 32, 32, 8, 4, false>
      <<<dim3(4, 4, 162), 256, 0, stream>>>(x4, nullptr, wdc, nullptr, nullptr, stats + 2048, xd, nullptr);
  bnfin_kernel<<<1, 128, 0, stream>>>(stats + 2048, gd, bbd, 32, 1.f / 663552.f);
  norm_ip<4><<<2048, 256, 0, stream>>>(xd, stats + 2048, 2654208L);

  mconv<0, 3, false, 32, 32, 16, 16, 1, 64, 64, 4, 4, false>
      <<<dim3(16, 1, 162), 256, 0, stream>>>(xd, nullptr, wc5, b5, nullptr, nullptr, nullptr, out);

  // DAP softmax + embedding reduction
  softmax_kernel<<<128, 64, 0, stream>>>(out, dapw, score);
  emb_kernel<<<1024, 256, 0, stream>>>(score, be3, out);

  (void)in_sizes; (void)n_in; (void)out_size; (void)ws_size;
}